// Round 7
// baseline (269.086 us; speedup 1.0000x reference)
//
#include <hip/hip_runtime.h>
#include <hip/hip_cooperative_groups.h>

namespace cg = cooperative_groups;

#define DD 128
#define VV 26
#define NW 13          // u16-packed words for 26 labels (register histograms)
#define CS8 8          // u32 words per u8-packed counts row (32 B)
#define G 256          // grid blocks == sort chunks
#define T 1024         // threads per block
#define TWIN 512       // node window for per-protein LDS counts table
#define PCS 260        // padded ints per pcum row (256 excl + total + pad)

__device__ __forceinline__ unsigned wsum(unsigned v) {
#pragma unroll
    for (int m = 32; m >= 1; m >>= 1) v += __shfl_xor(v, m, 64);
    return v;
}

// first p with ends[p] > t; guess via equal-size assumption, correct by walking
__device__ __forceinline__ int seg_guess(const int* ends, int B, int t, int Lavg) {
    int p = t / Lavg;
    if (p > B - 1) p = B - 1;
    while (p > 0 && ends[p - 1] > t) --p;
    while (ends[p] <= t) ++p;   // ends[B-1] == N > t always terminates
    return p;
}

// largest b in [0,G-1] with cumx[b] <= j  (cumx[0]==0)
__device__ __forceinline__ int bseg(const int* cumx, int j) {
    int lo = 0, hi = G - 1;
    while (lo < hi) {
        int mid = (lo + hi + 1) >> 1;
        if (cumx[mid] <= j) lo = mid; else hi = mid - 1;
    }
    return lo;
}

__global__ void __launch_bounds__(T, 4)
k_all(const int* __restrict__ src, const int* __restrict__ tgt,
      const int* __restrict__ x, const int* __restrict__ ends,
      int E, int B, int chunk, int Lavg,
      const float* __restrict__ emb, const float* __restrict__ W1r,
      const float* __restrict__ b1, const float* __restrict__ W1o,
      const float* __restrict__ W2r, const float* __restrict__ W2o,
      int* __restrict__ segstart, int* __restrict__ seghist,
      unsigned short* __restrict__ sorted_tl, unsigned* __restrict__ sorted_s,
      int* __restrict__ pcum, int* __restrict__ psegb,
      unsigned* __restrict__ counts, float* __restrict__ CpG, float* __restrict__ HpG,
      float* __restrict__ P1, float* __restrict__ P2, float* __restrict__ P3,
      float* __restrict__ uvec, float* __restrict__ wvec,
      const float* __restrict__ b2, float* __restrict__ out)
{
    extern __shared__ char smem[];
    cg::grid_group grid = cg::this_grid();
    int tid = threadIdx.x;
    int blk = blockIdx.x;
    int chunkp = (chunk + 1) & ~1;

    // ---- phase 0a: weight precompute on blocks < VV ----
    // P1 = E1@W2r^T, P2 = R1@W2r^T + E1@W2o^T, P3 = R1@W2o^T
    // (E1=emb@W1r^T, R1=emb@W1o^T); uvec = W2r@b1, wvec = W2o@b1.
    if (blk < VV) {
        float* e1r = (float*)smem;
        float* r1r = e1r + DD;
        float* b1s = r1r + DD;
        int v = blk, d = tid;
        if (d < DD) {
            const float* e = emb + v * DD;
            const float* w1r = W1r + d * DD;
            const float* w1o = W1o + d * DD;
            float s1 = 0.f, s2 = 0.f;
            for (int k = 0; k < DD; ++k) { float ev = e[k]; s1 += ev * w1r[k]; s2 += ev * w1o[k]; }
            e1r[d] = s1; r1r[d] = s2; b1s[d] = b1[d];
        }
        __syncthreads();
        if (d < DD) {
            const float* wr = W2r + d * DD;
            const float* wo = W2o + d * DD;
            float p1 = 0.f, p2 = 0.f, p3 = 0.f, su = 0.f, sw = 0.f;
            for (int k = 0; k < DD; ++k) {
                float a = wr[k], bb = wo[k], ee = e1r[k], r = r1r[k], c = b1s[k];
                p1 += ee * a; p2 += r * a + ee * bb; p3 += r * bb;
                su += c * a; sw += c * bb;
            }
            P1[v * DD + d] = p1; P2[v * DD + d] = p2; P3[v * DD + d] = p3;
            if (v == 0) { uvec[d] = su; wvec[d] = sw; }
        }
        __syncthreads();
    }

    // ---- phase 0b: chunk counting sort (hist -> scan -> LDS place -> coalesced out)
    {
        int* lds_ends = (int*)smem;                         // 1024
        int* scan = lds_ends + 1024;                        // 1024
        int* cur = scan + 1024;                             // 1024
        unsigned short* lpe = (unsigned short*)(cur + 1024); // chunkp
        unsigned short* stl = lpe + chunkp;                  // chunkp
        unsigned* sts = (unsigned*)(stl + chunkp);           // chunk

        int e0 = blk * chunk;
        int e1 = min(E, e0 + chunk);
        int clen = e1 - e0;
        for (int i = tid; i < B; i += T) lds_ends[i] = ends[i];
        scan[tid] = 0;
        __syncthreads();
        for (int i = tid; i < clen; i += T) {
            int t = tgt[e0 + i];
            int p = seg_guess(lds_ends, B, t, Lavg);
            atomicAdd(&scan[p], 1);
            lpe[i] = (unsigned short)p;
        }
        __syncthreads();
        int v = scan[tid];
        if (tid < B) seghist[blk * B + tid] = v;     // b-major, coalesced
        for (int off = 1; off < T; off <<= 1) {
            int t = (tid >= off) ? scan[tid - off] : 0;
            __syncthreads();
            scan[tid] += t;
            __syncthreads();
        }
        if (tid < B) {
            int excl = scan[tid] - v;
            cur[tid] = excl;
            segstart[blk * B + tid] = e0 + excl;
        }
        __syncthreads();
        for (int i = tid; i < clen; i += T) {
            int e = e0 + i;
            int p = lpe[i];
            int s = src[e];
            int t = tgt[e];
            int lbl = x[s];
            int pst = (p == 0) ? 0 : lds_ends[p - 1];
            int pos = atomicAdd(&cur[p], 1);
            stl[pos] = (unsigned short)(((t - pst) << 5) | lbl);   // Lp < 2048 required
            sts[pos] = (unsigned)s;
        }
        __syncthreads();
        for (int i = tid; i < clen; i += T) {
            sorted_tl[e0 + i] = stl[i];
            sorted_s[e0 + i] = sts[i];
        }
    }

    grid.sync();

    // ---- phase 1: one-time transpose + per-protein exclusive scan over chunks
    {
        int* h = (int*)smem;   // 256
        for (int p = blk; p < B; p += G) {
            int v = 0;
            if (tid < G) { v = seghist[tid * B + p]; h[tid] = v; }
            __syncthreads();
            for (int off = 1; off < G; off <<= 1) {
                int t = (tid >= off && tid < G) ? h[tid - off] : 0;
                __syncthreads();
                if (tid < G) h[tid] += t;
                __syncthreads();
            }
            if (tid < G) {
                pcum[p * PCS + tid] = h[tid] - v;                 // exclusive
                psegb[p * G + tid] = segstart[tid * B + p];       // transposed
            }
            if (tid == G - 1) pcum[p * PCS + G] = h[G - 1];       // Dp total
            __syncthreads();
        }
    }

    grid.sync();

    // ---- phase 2: u8-packed counts rows + Cp + Hp per protein ----
    {
        unsigned* tab = (unsigned*)smem;                 // TWIN*CS8 (16 KB)
        int* cumx = (int*)(smem + TWIN * CS8 * 4);       // 257 (+pad)
        int* segb = cumx + 260;                          // 256
        unsigned* red = (unsigned*)(segb + 256);         // 16*26

        for (int p = blk; p < B; p += G) {
            int start = (p == 0) ? 0 : ends[p - 1];
            int end = ends[p];
            int Lp = end - start;
            if (tid <= G) cumx[tid] = pcum[p * PCS + tid];
            if (tid < G) segb[tid] = psegb[p * G + tid];
            __syncthreads();
            int Dp = cumx[G];

            unsigned cpw[NW], hpw[NW];
#pragma unroll
            for (int w = 0; w < NW; ++w) { cpw[w] = 0u; hpw[w] = 0u; }

            // Hp: own-node labels (contiguous, coalesced)
            for (int i = start + tid; i < end; i += T) {
                int l = x[i];
                unsigned inc = 1u << ((l & 1) * 16);
                int wi = l >> 1;
#pragma unroll
                for (int w = 0; w < NW; ++w) hpw[w] += (w == wi) ? inc : 0u;
            }

            for (int w0 = 0; w0 < Lp; w0 += TWIN) {
                int wlen = min(TWIN, Lp - w0);
                __syncthreads();
                for (int i = tid; i < wlen * CS8; i += T) tab[i] = 0u;
                __syncthreads();
                for (int j = tid; j < Dp; j += T) {
                    int bb = bseg(cumx, j);
                    int pos = segb[bb] + (j - cumx[bb]);
                    unsigned tl = (unsigned)sorted_tl[pos];
                    int lbl = (int)(tl & 31u);
                    int tloc = (int)(tl >> 5) - w0;
                    if ((unsigned)tloc < (unsigned)wlen)
                        atomicAdd(&tab[tloc * CS8 + (lbl >> 2)], 1u << ((lbl & 3) * 8));
                    if (w0 == 0) {
                        unsigned inc = 1u << ((lbl & 1) * 16);
                        int wi = lbl >> 1;
#pragma unroll
                        for (int w = 0; w < NW; ++w) cpw[w] += (w == wi) ? inc : 0u;
                    }
                }
                __syncthreads();
                for (int idx = tid; idx < wlen * CS8; idx += T) {
                    int r = idx >> 3, w = idx & 7;
                    counts[((size_t)(start + w0 + r)) * CS8 + w] = tab[r * CS8 + w];
                }
            }

            int wave = tid >> 6, lane = tid & 63;
#pragma unroll
            for (int w = 0; w < NW; ++w) {
                unsigned a = wsum(cpw[w]); if (lane == 0) red[wave * 26 + w] = a;
                unsigned b = wsum(hpw[w]); if (lane == 0) red[wave * 26 + NW + w] = b;
            }
            __syncthreads();
            if (tid < 2 * NW) {
                unsigned t = 0;
#pragma unroll
                for (int w = 0; w < 16; ++w) t += red[w * 26 + tid];
                int grp = tid / NW, w = tid % NW;
                float* dst = (grp == 0) ? (CpG + (size_t)p * VV) : (HpG + (size_t)p * VV);
                dst[w * 2] = (float)(t & 0xFFFFu);
                if (w * 2 + 1 < VV) dst[w * 2 + 1] = (float)(t >> 16);
            }
            __syncthreads();
        }
    }

    grid.sync();

    // ---- phase 3: C2p via 32B u8-row gather + tiny epilogue ----
    {
        int* cumx = (int*)smem;                          // 257 (+pad)
        int* segb = cumx + 260;                          // 256
        unsigned* red = (unsigned*)(segb + 256);         // 16*14
        float* c2f = (float*)(red + 16 * 14);
        float* cpf = c2f + VV;
        float* hpf = cpf + VV;

        for (int p = blk; p < B; p += G) {
            int start = (p == 0) ? 0 : ends[p - 1];
            int end = ends[p];
            if (tid <= G) cumx[tid] = pcum[p * PCS + tid];
            if (tid < G) segb[tid] = psegb[p * G + tid];
            __syncthreads();
            int Dp = cumx[G];

            // u16-packed accumulators: ua[k] labels (4k,4k+2), ub[k] (4k+1,4k+3)
            unsigned ua[7], ub[7];
#pragma unroll
            for (int k = 0; k < 7; ++k) { ua[k] = 0u; ub[k] = 0u; }
            for (int j = tid; j < Dp; j += T) {
                int bb = bseg(cumx, j);
                int pos = segb[bb] + (j - cumx[bb]);
                int s = (int)sorted_s[pos];
                const uint4* cb = reinterpret_cast<const uint4*>(counts + (size_t)s * CS8);
                uint4 c0 = cb[0], c1 = cb[1];
                unsigned w;
                w = c0.x; ua[0] += w & 0x00FF00FFu; ub[0] += (w >> 8) & 0x00FF00FFu;
                w = c0.y; ua[1] += w & 0x00FF00FFu; ub[1] += (w >> 8) & 0x00FF00FFu;
                w = c0.z; ua[2] += w & 0x00FF00FFu; ub[2] += (w >> 8) & 0x00FF00FFu;
                w = c0.w; ua[3] += w & 0x00FF00FFu; ub[3] += (w >> 8) & 0x00FF00FFu;
                w = c1.x; ua[4] += w & 0x00FF00FFu; ub[4] += (w >> 8) & 0x00FF00FFu;
                w = c1.y; ua[5] += w & 0x00FF00FFu; ub[5] += (w >> 8) & 0x00FF00FFu;
                w = c1.z; ua[6] += w & 0x00FF00FFu; ub[6] += (w >> 8) & 0x00FF00FFu;
            }

            int wave = tid >> 6, lane = tid & 63;
#pragma unroll
            for (int k = 0; k < 7; ++k) {
                unsigned a = wsum(ua[k]); if (lane == 0) red[wave * 14 + 2 * k] = a;
                unsigned b = wsum(ub[k]); if (lane == 0) red[wave * 14 + 2 * k + 1] = b;
            }
            if (tid >= 64 && tid < 64 + VV)   cpf[tid - 64]  = CpG[(size_t)p * VV + (tid - 64)];
            if (tid >= 128 && tid < 128 + VV) hpf[tid - 128] = HpG[(size_t)p * VV + (tid - 128)];
            __syncthreads();
            if (tid < 14) {
                unsigned t = 0;
#pragma unroll
                for (int w = 0; w < 16; ++w) t += red[w * 14 + tid];
                int k = tid >> 1, isB = tid & 1;
                int base = 4 * k + isB;
                c2f[base] = (float)(t & 0xFFFFu);
                if (base + 2 < VV) c2f[base + 2] = (float)(t >> 16);
            }
            __syncthreads();
            if (tid < DD) {
                int d = tid;
                float acc = 0.f;
#pragma unroll
                for (int v = 0; v < VV; ++v)
                    acc += c2f[v] * P1[v * DD + d] + cpf[v] * P2[v * DD + d] + hpf[v] * P3[v * DD + d];
                float Lpf = (float)(end - start);
                float invL = 1.f / Lpf;
                out[(size_t)p * DD + d] = acc * invL + ((float)Dp * invL) * uvec[d] + wvec[d] + b2[d];
            }
            __syncthreads();
        }
    }
}

extern "C" void kernel_launch(void* const* d_in, const int* in_sizes, int n_in,
                              void* d_out, int out_size, void* d_ws, size_t ws_size,
                              hipStream_t stream) {
    const int*   x       = (const int*)d_in[0];
    const int*   edge    = (const int*)d_in[1];
    const int*   ends    = (const int*)d_in[2];
    const float* emb     = (const float*)d_in[3];
    const float* W_rel1  = (const float*)d_in[4];
    const float* b_rel1  = (const float*)d_in[5];
    const float* W_root1 = (const float*)d_in[6];
    const float* W_rel2  = (const float*)d_in[7];
    const float* b_rel2  = (const float*)d_in[8];
    const float* W_root2 = (const float*)d_in[9];

    int N = in_sizes[0];
    int E = in_sizes[1] / 2;
    int B = in_sizes[2];
    int Lavg = (N / B) > 0 ? (N / B) : 1;
    int chunk = (E + G - 1) / G;
    int chunkp = (chunk + 1) & ~1;

    const int* srcp = edge;
    const int* tgtp = edge + E;

    auto align256 = [](size_t v) { return (v + 255) & ~(size_t)255; };
    char* ws = (char*)d_ws;
    size_t off = 0;
    unsigned* counts = (unsigned*)(ws + off);                off += align256((size_t)N * CS8 * 4);
    int* segstart = (int*)(ws + off);                        off += align256((size_t)G * B * 4);
    int* seghist = (int*)(ws + off);                         off += align256((size_t)G * B * 4);
    unsigned short* sorted_tl = (unsigned short*)(ws + off); off += align256((size_t)E * 2);
    unsigned* sorted_s = (unsigned*)(ws + off);              off += align256((size_t)E * 4);
    int* pcum = (int*)(ws + off);                            off += align256((size_t)B * PCS * 4);
    int* psegb = (int*)(ws + off);                           off += align256((size_t)B * G * 4);
    float* CpG = (float*)(ws + off);                         off += align256((size_t)B * VV * 4);
    float* HpG = (float*)(ws + off);                         off += align256((size_t)B * VV * 4);
    float* P1 = (float*)(ws + off);                          off += align256((size_t)VV * DD * 4);
    float* P2 = (float*)(ws + off);                          off += align256((size_t)VV * DD * 4);
    float* P3 = (float*)(ws + off);                          off += align256((size_t)VV * DD * 4);
    float* uvec = (float*)(ws + off);                        off += align256((size_t)DD * 4);
    float* wvec = (float*)(ws + off);                        off += align256((size_t)DD * 4);
    (void)ws_size; (void)n_in; (void)out_size;

    float* outp = (float*)d_out;

    // no memsets: every workspace word consumed is written first in an earlier phase.

    size_t ldsb = (size_t)3 * 1024 * 4 + (size_t)chunkp * 4 + (size_t)chunk * 4;  // ~49.8 KB

    void* args[] = {
        (void*)&srcp, (void*)&tgtp, (void*)&x, (void*)&ends,
        (void*)&E, (void*)&B, (void*)&chunk, (void*)&Lavg,
        (void*)&emb, (void*)&W_rel1, (void*)&b_rel1, (void*)&W_root1,
        (void*)&W_rel2, (void*)&W_root2,
        (void*)&segstart, (void*)&seghist, (void*)&sorted_tl, (void*)&sorted_s,
        (void*)&pcum, (void*)&psegb,
        (void*)&counts, (void*)&CpG, (void*)&HpG,
        (void*)&P1, (void*)&P2, (void*)&P3, (void*)&uvec, (void*)&wvec,
        (void*)&b_rel2, (void*)&outp
    };
    hipLaunchCooperativeKernel((const void*)k_all, dim3(G), dim3(T), args,
                               (unsigned)ldsb, stream);
}

// Round 8
// 70.932 us; speedup vs baseline: 3.7936x; 3.7936x over previous
//
#include <hip/hip_runtime.h>

#define DD 128
#define VV 26
#define NW 13          // u16-packed words for 26 labels (register histograms)
#define CS8 8          // u32 words per u8-packed counts row (32 B)
#define G 256          // sort chunks == threads used for per-protein chunk tables
#define TWIN 512       // node window for per-protein LDS counts table

__device__ __forceinline__ unsigned wsum(unsigned v) {
#pragma unroll
    for (int m = 32; m >= 1; m >>= 1) v += __shfl_xor(v, m, 64);
    return v;
}

// inclusive scan within a 64-lane wave
__device__ __forceinline__ int wscan_incl(int v) {
    int lane = threadIdx.x & 63;
#pragma unroll
    for (int off = 1; off < 64; off <<= 1) {
        int t = __shfl_up(v, off, 64);
        if (lane >= off) v += t;
    }
    return v;
}

// first p with ends[p] > t; guess via equal-size assumption, correct by walking
__device__ __forceinline__ int seg_guess(const int* ends, int B, int t, int Lavg) {
    int p = t / Lavg;
    if (p > B - 1) p = B - 1;
    while (p > 0 && ends[p - 1] > t) --p;
    while (ends[p] <= t) ++p;   // ends[B-1] == N > t always terminates
    return p;
}

// largest b in [0,G-1] with cumx[b] <= j  (cumx[0]==0)
__device__ __forceinline__ int bseg(const int* cumx, int j) {
    int lo = 0, hi = G - 1;
    while (lo < hi) {
        int mid = (lo + hi + 1) >> 1;
        if (cumx[mid] <= j) lo = mid; else hi = mid - 1;
    }
    return lo;
}

// blocks [0,G): fused chunk counting-sort (hist -> shfl scan -> LDS place ->
//   coalesced writeout; payloads: u16 (tloc<<5|lbl), u32 src).
// blocks [G,G+VV): weight precompute
//   P1 = E1@W2r^T, P2 = R1@W2r^T + E1@W2o^T, P3 = R1@W2o^T (E1=emb@W1r^T, R1=emb@W1o^T)
//   uvec = W2r@b1, wvec = W2o@b1.
__global__ __launch_bounds__(1024)
void k_sort_pre(const int* __restrict__ src, const int* __restrict__ tgt,
                const int* __restrict__ x, const int* __restrict__ ends,
                int E, int B, int chunk, int Lavg,
                const float* __restrict__ emb,
                const float* __restrict__ W1r, const float* __restrict__ b1,
                const float* __restrict__ W1o,
                const float* __restrict__ W2r, const float* __restrict__ W2o,
                unsigned short* __restrict__ sorted_tl, unsigned* __restrict__ sorted_s,
                int* __restrict__ segstart, int* __restrict__ seghist,
                float* __restrict__ P1, float* __restrict__ P2,
                float* __restrict__ P3, float* __restrict__ uvec,
                float* __restrict__ wvec) {
    extern __shared__ int lds[];
    int tid = threadIdx.x;
    int chunkp = (chunk + 1) & ~1;

    if (blockIdx.x >= G) {
        // ---- precompute part ----
        float* e1r = (float*)lds;
        float* r1r = e1r + DD;
        float* b1s = r1r + DD;
        int v = blockIdx.x - G;
        int d = tid;
        if (d < DD) {
            const float* e = emb + v * DD;
            const float* w1r = W1r + d * DD;
            const float* w1o = W1o + d * DD;
            float s1 = 0.f, s2 = 0.f;
            for (int k = 0; k < DD; ++k) { float ev = e[k]; s1 += ev * w1r[k]; s2 += ev * w1o[k]; }
            e1r[d] = s1; r1r[d] = s2; b1s[d] = b1[d];
        }
        __syncthreads();
        if (d < DD) {
            const float* wr = W2r + d * DD;
            const float* wo = W2o + d * DD;
            float p1 = 0.f, p2 = 0.f, p3 = 0.f, su = 0.f, sw = 0.f;
            for (int k = 0; k < DD; ++k) {
                float a = wr[k], bb = wo[k], ee = e1r[k], r = r1r[k], c = b1s[k];
                p1 += ee * a; p2 += r * a + ee * bb; p3 += r * bb;
                su += c * a; sw += c * bb;
            }
            P1[v * DD + d] = p1; P2[v * DD + d] = p2; P3[v * DD + d] = p3;
            if (v == 0) { uvec[d] = su; wvec[d] = sw; }
        }
        return;
    }

    // ---- sort part ----
    int* lds_ends = lds;                                   // 1024
    int* hist = lds_ends + 1024;                           // 1024
    int* cur = hist + 1024;                                // 1024
    int* wsums = cur + 1024;                               // 16
    unsigned short* lpe = (unsigned short*)(wsums + 16);   // chunkp u16
    unsigned short* stl = lpe + chunkp;                    // chunkp u16
    unsigned* sts = (unsigned*)(stl + chunkp);             // chunk u32

    int b = blockIdx.x;
    int e0 = b * chunk;
    int e1 = min(E, e0 + chunk);
    int clen = e1 - e0;

    for (int i = tid; i < B; i += 1024) lds_ends[i] = ends[i];
    hist[tid] = 0;
    __syncthreads();

    for (int i = tid; i < clen; i += 1024) {
        int t = tgt[e0 + i];
        int p = seg_guess(lds_ends, B, t, Lavg);
        atomicAdd(&hist[p], 1);
        lpe[i] = (unsigned short)p;
    }
    __syncthreads();

    int v = hist[tid];
    if (tid < B) seghist[b * B + tid] = v;   // b-major, coalesced
    int wave = tid >> 6, lane = tid & 63;
    int incl = wscan_incl(v);
    if (lane == 63) wsums[wave] = incl;
    __syncthreads();
    int offw = 0;
    for (int w = 0; w < wave; ++w) offw += wsums[w];
    int excl = incl + offw - v;
    if (tid < B) {
        cur[tid] = excl;
        segstart[b * B + tid] = e0 + excl;
    }
    __syncthreads();

    for (int i = tid; i < clen; i += 1024) {
        int e = e0 + i;
        int p = lpe[i];
        int s = src[e];
        int t = tgt[e];
        int lbl = x[s];
        int pst = (p == 0) ? 0 : lds_ends[p - 1];
        int pos = atomicAdd(&cur[p], 1);
        stl[pos] = (unsigned short)(((t - pst) << 5) | lbl);   // Lp < 2048 required
        sts[pos] = (unsigned)s;
    }
    __syncthreads();

    for (int i = tid; i < clen; i += 1024) {
        sorted_tl[e0 + i] = stl[i];
        sorted_s[e0 + i] = sts[i];
    }
}

// tiled transpose of seghist/segstart: [G][B] b-major -> [B][G] p-major
__global__ __launch_bounds__(256)
void k_trans(const int* __restrict__ a, const int* __restrict__ c, int B,
             int* __restrict__ aT, int* __restrict__ cT) {
    __shared__ int ta[32][33], tc[32][33];
    int b0 = blockIdx.x * 32;            // chunk dim, grid.x == G/32
    int p0 = blockIdx.y * 32;            // protein dim
    int tx = threadIdx.x & 31, ty = threadIdx.x >> 5;   // 32 x 8
    for (int r = ty; r < 32; r += 8) {
        int bb = b0 + r, pp = p0 + tx;
        if (pp < B) { ta[r][tx] = a[bb * B + pp]; tc[r][tx] = c[bb * B + pp]; }
    }
    __syncthreads();
    for (int r = ty; r < 32; r += 8) {
        int pp = p0 + r, bb = b0 + tx;
        if (pp < B) { aT[pp * G + bb] = ta[tx][r]; cT[pp * G + bb] = tc[tx][r]; }
    }
}

// one block per protein: u8-packed counts rows in LDS from the protein's edges
// (flattened over G chunk segments, coalesced p-major tables); emit Cp, Hp.
__global__ __launch_bounds__(256)
void k_counts(const int* __restrict__ x, const int* __restrict__ ends,
              const int* __restrict__ seghistT, const int* __restrict__ segstartT,
              int B, int E, const unsigned short* __restrict__ sorted_tl,
              unsigned* __restrict__ counts,
              float* __restrict__ CpG, float* __restrict__ HpG) {
    __shared__ unsigned tab[TWIN * CS8];            // 16 KB
    __shared__ int cumx[G + 4], segb[G], wsums[4];
    __shared__ unsigned red[4][2 * NW];
    int p = blockIdx.x, tid = threadIdx.x;
    int wave = tid >> 6, lane = tid & 63;
    int start = (p == 0) ? 0 : ends[p - 1];
    int end = ends[p];
    int Lp = end - start;

    int h = seghistT[p * G + tid];          // coalesced
    segb[tid] = segstartT[p * G + tid];     // coalesced
    int incl = wscan_incl(h);
    if (lane == 63) wsums[wave] = incl;
    __syncthreads();
    int offw = 0;
    for (int w = 0; w < wave; ++w) offw += wsums[w];
    cumx[tid] = incl + offw - h;
    if (tid == 255) cumx[G] = incl + offw;
    __syncthreads();
    int Dp = cumx[G];

    unsigned cpw[NW], hpw[NW];
#pragma unroll
    for (int w = 0; w < NW; ++w) { cpw[w] = 0u; hpw[w] = 0u; }

    // Hp: own-node labels (contiguous, coalesced)
    for (int i = start + tid; i < end; i += 256) {
        int l = x[i];
        unsigned inc = 1u << ((l & 1) * 16);
        int wi = l >> 1;
#pragma unroll
        for (int w = 0; w < NW; ++w) hpw[w] += (w == wi) ? inc : 0u;
    }

    // counts rows (u8 fields; per-node per-label in-degree << 256 for this data)
    for (int w0 = 0; w0 < Lp; w0 += TWIN) {
        int wlen = min(TWIN, Lp - w0);
        __syncthreads();
        for (int i = tid; i < wlen * CS8; i += 256) tab[i] = 0u;
        __syncthreads();
        for (int j = tid; j < Dp; j += 256) {
            int bb = bseg(cumx, j);
            int pos = segb[bb] + (j - cumx[bb]);
            unsigned tl = (unsigned)sorted_tl[pos];
            int lbl = (int)(tl & 31u);
            int tloc = (int)(tl >> 5) - w0;
            if ((unsigned)tloc < (unsigned)wlen)
                atomicAdd(&tab[tloc * CS8 + (lbl >> 2)], 1u << ((lbl & 3) * 8));
            if (w0 == 0) {
                unsigned inc = 1u << ((lbl & 1) * 16);
                int wi = lbl >> 1;
#pragma unroll
                for (int w = 0; w < NW; ++w) cpw[w] += (w == wi) ? inc : 0u;
            }
        }
        __syncthreads();
        for (int idx = tid; idx < wlen * CS8; idx += 256) {
            int r = idx >> 3, w = idx & 7;
            counts[((size_t)(start + w0 + r)) * CS8 + w] = tab[r * CS8 + w];
        }
    }

#pragma unroll
    for (int w = 0; w < NW; ++w) {
        unsigned a = wsum(cpw[w]); if (lane == 0) red[wave][w] = a;
        unsigned b = wsum(hpw[w]); if (lane == 0) red[wave][NW + w] = b;
    }
    __syncthreads();
    if (tid < 2 * NW) {
        unsigned t = red[0][tid] + red[1][tid] + red[2][tid] + red[3][tid];
        int grp = tid / NW, w = tid % NW;
        float* dst = (grp == 0) ? (CpG + (size_t)p * VV) : (HpG + (size_t)p * VV);
        dst[w * 2] = (float)(t & 0xFFFFu);
        if (w * 2 + 1 < VV) dst[w * 2 + 1] = (float)(t >> 16);
    }
}

// one block per protein: C2p via 32B u8-row gather over bucket sources + epilogue
__global__ __launch_bounds__(256)
void k_protein(const int* __restrict__ ends,
               const int* __restrict__ seghistT, const int* __restrict__ segstartT,
               const unsigned* __restrict__ sorted_s,
               const unsigned* __restrict__ counts,
               const float* __restrict__ CpG, const float* __restrict__ HpG,
               const float* __restrict__ P1, const float* __restrict__ P2,
               const float* __restrict__ P3, const float* __restrict__ uvec,
               const float* __restrict__ wvec, const float* __restrict__ b2,
               int B, int E, float* __restrict__ out) {
    __shared__ int cumx[G + 4], segb[G], wsums[4];
    __shared__ unsigned red[4][14];
    __shared__ float c2f[VV], cpf[VV], hpf[VV];
    int p = blockIdx.x, tid = threadIdx.x;
    int wave = tid >> 6, lane = tid & 63;
    int start = (p == 0) ? 0 : ends[p - 1];
    int end = ends[p];

    int h = seghistT[p * G + tid];          // coalesced
    segb[tid] = segstartT[p * G + tid];     // coalesced
    int incl = wscan_incl(h);
    if (lane == 63) wsums[wave] = incl;
    __syncthreads();
    int offw = 0;
    for (int w = 0; w < wave; ++w) offw += wsums[w];
    cumx[tid] = incl + offw - h;
    if (tid == 255) cumx[G] = incl + offw;
    __syncthreads();
    int Dp = cumx[G];

    // u16-packed accumulators: ua[k] holds labels (4k,4k+2), ub[k] (4k+1,4k+3)
    unsigned ua[7], ub[7];
#pragma unroll
    for (int k = 0; k < 7; ++k) { ua[k] = 0u; ub[k] = 0u; }
    for (int j = tid; j < Dp; j += 256) {
        int bb = bseg(cumx, j);
        int pos = segb[bb] + (j - cumx[bb]);
        int s = (int)sorted_s[pos];
        const uint4* cb = reinterpret_cast<const uint4*>(counts + (size_t)s * CS8);
        uint4 c0 = cb[0], c1 = cb[1];
        unsigned w;
        w = c0.x; ua[0] += w & 0x00FF00FFu; ub[0] += (w >> 8) & 0x00FF00FFu;
        w = c0.y; ua[1] += w & 0x00FF00FFu; ub[1] += (w >> 8) & 0x00FF00FFu;
        w = c0.z; ua[2] += w & 0x00FF00FFu; ub[2] += (w >> 8) & 0x00FF00FFu;
        w = c0.w; ua[3] += w & 0x00FF00FFu; ub[3] += (w >> 8) & 0x00FF00FFu;
        w = c1.x; ua[4] += w & 0x00FF00FFu; ub[4] += (w >> 8) & 0x00FF00FFu;
        w = c1.y; ua[5] += w & 0x00FF00FFu; ub[5] += (w >> 8) & 0x00FF00FFu;
        w = c1.z; ua[6] += w & 0x00FF00FFu; ub[6] += (w >> 8) & 0x00FF00FFu;
    }

#pragma unroll
    for (int k = 0; k < 7; ++k) {
        unsigned a = wsum(ua[k]); if (lane == 0) red[wave][2 * k] = a;
        unsigned b = wsum(ub[k]); if (lane == 0) red[wave][2 * k + 1] = b;
    }
    if (tid >= 64 && tid < 64 + VV)   cpf[tid - 64]  = CpG[(size_t)p * VV + (tid - 64)];
    if (tid >= 128 && tid < 128 + VV) hpf[tid - 128] = HpG[(size_t)p * VV + (tid - 128)];
    __syncthreads();
    if (tid < 14) {
        unsigned t = red[0][tid] + red[1][tid] + red[2][tid] + red[3][tid];
        int k = tid >> 1, isB = tid & 1;
        int base = 4 * k + isB;
        c2f[base] = (float)(t & 0xFFFFu);
        if (base + 2 < VV) c2f[base + 2] = (float)(t >> 16);
    }
    __syncthreads();

    if (tid < DD) {
        int d = tid;
        float acc = 0.f;
#pragma unroll
        for (int v = 0; v < VV; ++v)
            acc += c2f[v] * P1[v * DD + d] + cpf[v] * P2[v * DD + d] + hpf[v] * P3[v * DD + d];
        float Lp = (float)(end - start);
        float invL = 1.f / Lp;
        float Dpf = (float)Dp;
        out[(size_t)p * DD + d] = acc * invL + (Dpf * invL) * uvec[d] + wvec[d] + b2[d];
    }
}

extern "C" void kernel_launch(void* const* d_in, const int* in_sizes, int n_in,
                              void* d_out, int out_size, void* d_ws, size_t ws_size,
                              hipStream_t stream) {
    const int*   x       = (const int*)d_in[0];
    const int*   edge    = (const int*)d_in[1];
    const int*   ends    = (const int*)d_in[2];
    const float* emb     = (const float*)d_in[3];
    const float* W_rel1  = (const float*)d_in[4];
    const float* b_rel1  = (const float*)d_in[5];
    const float* W_root1 = (const float*)d_in[6];
    const float* W_rel2  = (const float*)d_in[7];
    const float* b_rel2  = (const float*)d_in[8];
    const float* W_root2 = (const float*)d_in[9];

    const int N = in_sizes[0];
    const int E = in_sizes[1] / 2;
    const int B = in_sizes[2];
    const int Lavg = (N / B) > 0 ? (N / B) : 1;
    const int chunk = (E + G - 1) / G;
    const int chunkp = (chunk + 1) & ~1;

    const int* srcp = edge;
    const int* tgtp = edge + E;

    auto align256 = [](size_t v) { return (v + 255) & ~(size_t)255; };
    char* ws = (char*)d_ws;
    size_t off = 0;
    unsigned* counts = (unsigned*)(ws + off);                off += align256((size_t)N * CS8 * 4);
    int* segstart = (int*)(ws + off);                        off += align256((size_t)G * B * 4);
    int* seghist = (int*)(ws + off);                         off += align256((size_t)G * B * 4);
    int* segstartT = (int*)(ws + off);                       off += align256((size_t)B * G * 4);
    int* seghistT = (int*)(ws + off);                        off += align256((size_t)B * G * 4);
    unsigned short* sorted_tl = (unsigned short*)(ws + off); off += align256((size_t)E * 2);
    unsigned* sorted_s = (unsigned*)(ws + off);              off += align256((size_t)E * 4);
    float* CpG = (float*)(ws + off);                         off += align256((size_t)B * VV * 4);
    float* HpG = (float*)(ws + off);                         off += align256((size_t)B * VV * 4);
    float* P1 = (float*)(ws + off);                          off += align256((size_t)VV * DD * 4);
    float* P2 = (float*)(ws + off);                          off += align256((size_t)VV * DD * 4);
    float* P3 = (float*)(ws + off);                          off += align256((size_t)VV * DD * 4);
    float* uvec = (float*)(ws + off);                        off += align256((size_t)DD * 4);
    float* wvec = (float*)(ws + off);                        off += align256((size_t)DD * 4);
    (void)ws_size; (void)n_in; (void)out_size;

    // no memsets: every workspace word consumed is written first by a kernel.

    size_t ldsb = (size_t)(3 * 1024 + 16) * 4 + (size_t)chunkp * 4 + (size_t)chunk * 4;
    k_sort_pre<<<G + VV, 1024, ldsb, stream>>>(
        srcp, tgtp, x, ends, E, B, chunk, Lavg,
        emb, W_rel1, b_rel1, W_root1, W_rel2, W_root2,
        sorted_tl, sorted_s, segstart, seghist, P1, P2, P3, uvec, wvec);

    dim3 tgrid(G / 32, (B + 31) / 32);
    k_trans<<<tgrid, 256, 0, stream>>>(seghist, segstart, B, seghistT, segstartT);

    k_counts<<<B, 256, 0, stream>>>(x, ends, seghistT, segstartT, B, E, sorted_tl,
                                    counts, CpG, HpG);

    k_protein<<<B, 256, 0, stream>>>(ends, seghistT, segstartT, sorted_s, counts, CpG, HpG,
                                     P1, P2, P3, uvec, wvec, b_rel2, B, E, (float*)d_out);
}